// Round 6
// baseline (300.513 us; speedup 1.0000x reference)
//
#include <hip/hip_runtime.h>
#include <cstddef>

#define NN   50000
#define KNB  32

typedef _Float16 h2    __attribute__((ext_vector_type(2)));
typedef _Float16 half8 __attribute__((ext_vector_type(8)));
typedef float    f4    __attribute__((ext_vector_type(4)));
typedef float    f8    __attribute__((ext_vector_type(8)));

// ---------------- prep: W1^T and W2^T as fp16 [N][K] ----------------------
__global__ __launch_bounds__(256) void prep(const float* __restrict__ W1,
                                            const float* __restrict__ W2,
                                            _Float16* __restrict__ w1t,
                                            _Float16* __restrict__ w2t) {
  const int id = blockIdx.x * 256 + threadIdx.x;
  if (id < 128 * 512) {                     // w1t[n][k] = W1[k][n]
    const int n = id >> 9, k = id & 511;
    w1t[id] = (_Float16)W1[k * 128 + n];
  } else {
    const int id2 = id - 128 * 512;
    if (id2 < 64 * 128) {                   // w2t[n][k] = W2[k][n]
      const int n = id2 >> 7, k = id2 & 127;
      w2t[id2] = (_Float16)W2[k * 64 + n];
    }
  }
}

// ---------------- GEMM1: H1[M,128] = A[M,512]fp32 @ W1 + b1, fp16 out -----
// MFMA f32_16x16x32_f16. Latency-oriented layout: wave = 16 rows x 64 cols
// (4 n-tiles) -> 2x the waves of the 128-col version (24 waves/CU), and the
// A-fragment for the next K-step is prefetched before this step's MFMAs.
// Block = 32 rows x 128 cols (2 m-subtiles x 2 col-halves).
//   A: m=lane&15, k=(lane>>4)*8+j   B(=W^T row): n=lane&15, same k
//   C/D: col=lane&15, row=(lane>>4)*4+reg   (verified in R5)
__global__ __launch_bounds__(256) void gemm1_mfma(
    const float* __restrict__ A, const _Float16* __restrict__ Bt,
    const float* __restrict__ bias, _Float16* __restrict__ C, int M) {
  constexpr int K = 512;
  const int wave  = threadIdx.x >> 6;
  const int lane  = threadIdx.x & 63;
  const int nhalf = wave & 1;                 // col half: 0 -> cols 0..63, 1 -> 64..127
  const int m0    = blockIdx.x * 32 + (wave >> 1) * 16;
  const int mr    = lane & 15;
  const int kg    = lane >> 4;

  int arow = m0 + mr;
  if (arow >= M) arow = M - 1;                // clamp; garbage rows dropped at store
  const float*    ap = A  + (size_t)arow * K + kg * 8;
  const _Float16* bp = Bt + (size_t)(nhalf * 64 + mr) * K + kg * 8;

  f4 acc[4] = {};

  f4 a0 = *(const f4*)ap;                     // prefetch k-step 0
  f4 a1 = *(const f4*)(ap + 4);

  #pragma unroll 4
  for (int k0 = 0; k0 < K; k0 += 32) {
    const f8 av = {a0[0], a0[1], a0[2], a0[3], a1[0], a1[1], a1[2], a1[3]};
    const half8 af = __builtin_convertvector(av, half8);
    if (k0 + 32 < K) {                        // prefetch next before MFMAs
      ap += 32;
      a0 = *(const f4*)ap;
      a1 = *(const f4*)(ap + 4);
    }
    #pragma unroll
    for (int nt = 0; nt < 4; ++nt) {
      const half8 bf = *(const half8*)(bp + (size_t)nt * 16 * K);
      acc[nt] = __builtin_amdgcn_mfma_f32_16x16x32_f16(af, bf, acc[nt], 0, 0, 0);
    }
    bp += 32;
  }

  #pragma unroll
  for (int nt = 0; nt < 4; ++nt) {
    const int col = nhalf * 64 + nt * 16 + mr;
    const float bv = bias[col];
    #pragma unroll
    for (int r = 0; r < 4; ++r) {
      const int row = m0 + kg * 4 + r;
      if (row < M)
        C[(size_t)row * 128 + col] = (_Float16)(acc[nt][r] + bv);
    }
  }
}

// ---------------- GEMM2: H2[M,64] = A[M,128]fp16 @ W2 + b2, fp16 out ------
// Wave = 16 rows x 32 cols (2 n-tiles); block = 32 rows x 64 cols.
__global__ __launch_bounds__(256) void gemm2_mfma(
    const _Float16* __restrict__ A, const _Float16* __restrict__ Bt,
    const float* __restrict__ bias, _Float16* __restrict__ C, int M) {
  constexpr int K = 128;
  const int wave  = threadIdx.x >> 6;
  const int lane  = threadIdx.x & 63;
  const int nhalf = wave & 1;                 // cols 0..31 or 32..63
  const int m0    = blockIdx.x * 32 + (wave >> 1) * 16;
  const int mr    = lane & 15;
  const int kg    = lane >> 4;

  int arow = m0 + mr;
  if (arow >= M) arow = M - 1;
  const _Float16* ap = A  + (size_t)arow * K + kg * 8;
  const _Float16* bp = Bt + (size_t)(nhalf * 32 + mr) * K + kg * 8;

  f4 acc[2] = {};

  half8 af = *(const half8*)ap;               // prefetch k-step 0

  #pragma unroll
  for (int k0 = 0; k0 < K; k0 += 32) {
    const half8 cur = af;
    if (k0 + 32 < K) {
      ap += 32;
      af = *(const half8*)ap;
    }
    #pragma unroll
    for (int nt = 0; nt < 2; ++nt) {
      const half8 bf = *(const half8*)(bp + (size_t)nt * 16 * K);
      acc[nt] = __builtin_amdgcn_mfma_f32_16x16x32_f16(cur, bf, acc[nt], 0, 0, 0);
    }
    bp += 32;
  }

  #pragma unroll
  for (int nt = 0; nt < 2; ++nt) {
    const int col = nhalf * 32 + nt * 16 + mr;
    const float bv = bias[col];
    #pragma unroll
    for (int r = 0; r < 4; ++r) {
      const int row = m0 + kg * 4 + r;
      if (row < M)
        C[(size_t)row * 64 + col] = (_Float16)(acc[nt][r] + bv);
    }
  }
}

// ---------------- median machinery (unchanged from R4/R5) -----------------
__device__ __forceinline__ void ceh(h2& a, h2& b) {
  h2 lo = __builtin_elementwise_min(a, b);
  h2 hi = __builtin_elementwise_max(a, b);
  a = lo;
  b = hi;
}

// Batcher odd-even mergesort, 32 h2 elements; only v[15] consumed -> DCE.
__device__ __forceinline__ void sort32h(h2 (&v)[32]) {
  #pragma unroll
  for (int p = 1; p < 32; p <<= 1) {
    #pragma unroll
    for (int k = p; k >= 1; k >>= 1) {
      #pragma unroll
      for (int j = k & (p - 1); j + k < 32; j += 2 * k) {
        #pragma unroll
        for (int i = 0; i < k; ++i) {
          if (i + j + k < 32) {
            if ((i + j) / (2 * p) == (i + j + k) / (2 * p)) {
              ceh(v[i + j], v[i + j + k]);
            }
          }
        }
      }
    }
  }
}

// Median over 32 neighbor rows (layer 1, D=128) + ReLU. One wave per node.
__global__ __launch_bounds__(256) void median_relu1(const h2* __restrict__ H,
                                                    const int* __restrict__ nb,
                                                    h2* __restrict__ O) {
  const int node = blockIdx.x * 4 + (threadIdx.x >> 6);
  const int lane = threadIdx.x & 63;
  const int* nrow = nb + (size_t)node * KNB;
  h2 v[32];
  #pragma unroll
  for (int j = 0; j < KNB; ++j) {
    const int idx = nrow[j];
    v[j] = H[(size_t)idx * 64 + lane];
  }
  sort32h(v);
  const h2 z = (h2)((_Float16)0);
  O[(size_t)node * 64 + lane] = __builtin_elementwise_max(v[15], z);
}

// Median over 32 neighbor rows (layer 2, D=64); fp32 output.
__global__ __launch_bounds__(256) void median2(const h2* __restrict__ H,
                                               const int* __restrict__ nb,
                                               float2* __restrict__ O) {
  const int node = blockIdx.x * 8 + (threadIdx.x >> 5);
  const int lane = threadIdx.x & 31;
  const int* nrow = nb + (size_t)node * KNB;
  h2 v[32];
  #pragma unroll
  for (int j = 0; j < KNB; ++j) {
    const int idx = nrow[j];
    v[j] = H[(size_t)idx * 32 + lane];
  }
  sort32h(v);
  float2 o;
  o.x = (float)v[15][0];
  o.y = (float)v[15][1];
  O[(size_t)node * 32 + lane] = o;
}

extern "C" void kernel_launch(void* const* d_in, const int* in_sizes, int n_in,
                              void* d_out, int out_size, void* d_ws, size_t ws_size,
                              hipStream_t stream) {
  const float* feat = (const float*)d_in[0];   // [50000,512]
  const float* W1   = (const float*)d_in[1];   // [512,128]
  const float* b1   = (const float*)d_in[2];   // [128]
  const float* W2   = (const float*)d_in[3];   // [128,64]
  const float* b2   = (const float*)d_in[4];   // [64]
  const int*   nb   = (const int*)d_in[5];     // [50000,32]
  float* out = (float*)d_out;                  // [50000,64] fp32

  _Float16* h1   = (_Float16*)d_ws;                 // 12.8 MB
  _Float16* med1 = h1 + (size_t)NN * 128;           // 12.8 MB
  _Float16* w1t  = med1 + (size_t)NN * 128;         // 128 KB  [128][512]
  _Float16* w2t  = w1t + 128 * 512;                 // 16 KB   [64][128]
  _Float16* h2b  = h1;                              // reuse (h1 dead)

  prep<<<dim3(288), dim3(256), 0, stream>>>(W1, W2, w1t, w2t);
  gemm1_mfma<<<dim3((NN + 31) / 32), dim3(256), 0, stream>>>(feat, w1t, b1, h1, NN);
  median_relu1<<<dim3(NN / 4), dim3(256), 0, stream>>>(
      (const h2*)h1, nb, (h2*)med1);
  gemm2_mfma<<<dim3((NN + 31) / 32), dim3(256), 0, stream>>>(med1, w2t, b2, h2b, NN);
  median2<<<dim3(NN / 8), dim3(256), 0, stream>>>(
      (const h2*)h2b, nb, (float2*)out);
}

// Round 7
// 292.101 us; speedup vs baseline: 1.0288x; 1.0288x over previous
//
#include <hip/hip_runtime.h>
#include <cstddef>

#define NN   50000
#define KNB  32

typedef _Float16 h2    __attribute__((ext_vector_type(2)));
typedef _Float16 half8 __attribute__((ext_vector_type(8)));
typedef float    f4    __attribute__((ext_vector_type(4)));
typedef float    f8    __attribute__((ext_vector_type(8)));

// ---------------- prep: W1^T and W2^T as fp16 [N][K] ----------------------
__global__ __launch_bounds__(256) void prep(const float* __restrict__ W1,
                                            const float* __restrict__ W2,
                                            _Float16* __restrict__ w1t,
                                            _Float16* __restrict__ w2t) {
  const int id = blockIdx.x * 256 + threadIdx.x;
  if (id < 128 * 512) {                     // w1t[n][k] = W1[k][n]
    const int n = id >> 9, k = id & 511;
    w1t[id] = (_Float16)W1[k * 128 + n];
  } else {
    const int id2 = id - 128 * 512;
    if (id2 < 64 * 128) {                   // w2t[n][k] = W2[k][n]
      const int n = id2 >> 7, k = id2 & 127;
      w2t[id2] = (_Float16)W2[k * 64 + n];
    }
  }
}

// ---------------- GEMM1: H1[M,128] = A[M,512]fp32 @ W1 + b1, fp16 out -----
// R6 post-mortem: latency-bound with ~1 wave's loads in flight per CU.
// R7: deep per-wave MLP. Wave = 16 rows x 128 cols (A read exactly once).
// A pipelined 4 K-steps deep (8 KB/wave outstanding); B double-buffered
// one K-step ahead (8 KB/wave). 16 K-steps of 8 MFMAs.
//   A: m=lane&15, k=(lane>>4)*8+j   B(=W^T row): n=lane&15, same k
//   C/D: col=lane&15, row=(lane>>4)*4+reg   (verified R5/R6)
__global__ __launch_bounds__(256) void gemm1_mfma(
    const float* __restrict__ A, const _Float16* __restrict__ Bt,
    const float* __restrict__ bias, _Float16* __restrict__ C, int M) {
  constexpr int K = 512, NSTEP = 16, PF = 4;
  const int wave = threadIdx.x >> 6;
  const int lane = threadIdx.x & 63;
  const int m0   = (blockIdx.x * 4 + wave) * 16;
  const int mr   = lane & 15;
  const int kg   = lane >> 4;

  int arow = m0 + mr;
  if (arow >= M) arow = M - 1;              // clamp; garbage rows dropped at store
  const float*    ap = A  + (size_t)arow * K + kg * 8;
  const _Float16* bp = Bt + (size_t)mr * K + kg * 8;

  f4 acc[8] = {};

  // A pipeline: 4 K-steps in flight
  f4 abuf[PF][2];
  #pragma unroll
  for (int p = 0; p < PF; ++p) {
    abuf[p][0] = *(const f4*)(ap + p * 32);
    abuf[p][1] = *(const f4*)(ap + p * 32 + 4);
  }
  // B double buffer: step 0 in flight
  half8 bb[2][8];
  #pragma unroll
  for (int nt = 0; nt < 8; ++nt)
    bb[0][nt] = *(const half8*)(bp + (size_t)nt * 16 * K);

  #pragma unroll
  for (int s = 0; s < NSTEP; ++s) {
    const int cur = s & 1;
    // prefetch next step's B before consuming this step
    if (s + 1 < NSTEP) {
      const _Float16* bq = bp + (s + 1) * 32;
      #pragma unroll
      for (int nt = 0; nt < 8; ++nt)
        bb[cur ^ 1][nt] = *(const half8*)(bq + (size_t)nt * 16 * K);
    }
    // convert this step's A (loaded PF steps ago)
    const f4 a0 = abuf[s & (PF - 1)][0];
    const f4 a1 = abuf[s & (PF - 1)][1];
    const f8 av = {a0[0], a0[1], a0[2], a0[3], a1[0], a1[1], a1[2], a1[3]};
    const half8 af = __builtin_convertvector(av, half8);
    // refill the A slot PF steps ahead
    if (s + PF < NSTEP) {
      abuf[s & (PF - 1)][0] = *(const f4*)(ap + (s + PF) * 32);
      abuf[s & (PF - 1)][1] = *(const f4*)(ap + (s + PF) * 32 + 4);
    }
    #pragma unroll
    for (int nt = 0; nt < 8; ++nt)
      acc[nt] = __builtin_amdgcn_mfma_f32_16x16x32_f16(af, bb[cur][nt],
                                                       acc[nt], 0, 0, 0);
  }

  #pragma unroll
  for (int nt = 0; nt < 8; ++nt) {
    const int col = nt * 16 + mr;
    const float bv = bias[col];
    #pragma unroll
    for (int r = 0; r < 4; ++r) {
      const int row = m0 + kg * 4 + r;
      if (row < M)
        C[(size_t)row * 128 + col] = (_Float16)(acc[nt][r] + bv);
    }
  }
}

// ---------------- GEMM2: H2[M,64] = A[M,128]fp16 @ W2 + b2, fp16 out ------
// K=128 fits in registers: issue ALL loads (4 A-frags + 16 B-frags) up
// front -> 20 outstanding loads per wave, then 16 MFMAs. Wave = 16 rows x
// all 64 cols (A read once).
__global__ __launch_bounds__(256) void gemm2_mfma(
    const _Float16* __restrict__ A, const _Float16* __restrict__ Bt,
    const float* __restrict__ bias, _Float16* __restrict__ C, int M) {
  constexpr int K = 128;
  const int wave = threadIdx.x >> 6;
  const int lane = threadIdx.x & 63;
  const int m0   = (blockIdx.x * 4 + wave) * 16;
  const int mr   = lane & 15;
  const int kg   = lane >> 4;

  int arow = m0 + mr;
  if (arow >= M) arow = M - 1;
  const _Float16* ap = A  + (size_t)arow * K + kg * 8;
  const _Float16* bp = Bt + (size_t)mr * K + kg * 8;

  half8 afr[4];
  #pragma unroll
  for (int s = 0; s < 4; ++s) afr[s] = *(const half8*)(ap + s * 32);

  half8 bfr[4][4];                          // [nt][step]
  #pragma unroll
  for (int nt = 0; nt < 4; ++nt)
    #pragma unroll
    for (int s = 0; s < 4; ++s)
      bfr[nt][s] = *(const half8*)(bp + (size_t)nt * 16 * K + s * 32);

  f4 acc[4] = {};
  #pragma unroll
  for (int s = 0; s < 4; ++s)
    #pragma unroll
    for (int nt = 0; nt < 4; ++nt)
      acc[nt] = __builtin_amdgcn_mfma_f32_16x16x32_f16(afr[s], bfr[nt][s],
                                                       acc[nt], 0, 0, 0);

  #pragma unroll
  for (int nt = 0; nt < 4; ++nt) {
    const int col = nt * 16 + mr;
    const float bv = bias[col];
    #pragma unroll
    for (int r = 0; r < 4; ++r) {
      const int row = m0 + kg * 4 + r;
      if (row < M)
        C[(size_t)row * 64 + col] = (_Float16)(acc[nt][r] + bv);
    }
  }
}

// ---------------- median machinery (unchanged) ----------------------------
__device__ __forceinline__ void ceh(h2& a, h2& b) {
  h2 lo = __builtin_elementwise_min(a, b);
  h2 hi = __builtin_elementwise_max(a, b);
  a = lo;
  b = hi;
}

// Batcher odd-even mergesort, 32 h2 elements; only v[15] consumed -> DCE.
__device__ __forceinline__ void sort32h(h2 (&v)[32]) {
  #pragma unroll
  for (int p = 1; p < 32; p <<= 1) {
    #pragma unroll
    for (int k = p; k >= 1; k >>= 1) {
      #pragma unroll
      for (int j = k & (p - 1); j + k < 32; j += 2 * k) {
        #pragma unroll
        for (int i = 0; i < k; ++i) {
          if (i + j + k < 32) {
            if ((i + j) / (2 * p) == (i + j + k) / (2 * p)) {
              ceh(v[i + j], v[i + j + k]);
            }
          }
        }
      }
    }
  }
}

// Median over 32 neighbor rows (layer 1, D=128) + ReLU. One wave per node.
__global__ __launch_bounds__(256) void median_relu1(const h2* __restrict__ H,
                                                    const int* __restrict__ nb,
                                                    h2* __restrict__ O) {
  const int node = blockIdx.x * 4 + (threadIdx.x >> 6);
  const int lane = threadIdx.x & 63;
  const int* nrow = nb + (size_t)node * KNB;
  h2 v[32];
  #pragma unroll
  for (int j = 0; j < KNB; ++j) {
    const int idx = nrow[j];
    v[j] = H[(size_t)idx * 64 + lane];
  }
  sort32h(v);
  const h2 z = (h2)((_Float16)0);
  O[(size_t)node * 64 + lane] = __builtin_elementwise_max(v[15], z);
}

// Median over 32 neighbor rows (layer 2, D=64); fp32 output.
__global__ __launch_bounds__(256) void median2(const h2* __restrict__ H,
                                               const int* __restrict__ nb,
                                               float2* __restrict__ O) {
  const int node = blockIdx.x * 8 + (threadIdx.x >> 5);
  const int lane = threadIdx.x & 31;
  const int* nrow = nb + (size_t)node * KNB;
  h2 v[32];
  #pragma unroll
  for (int j = 0; j < KNB; ++j) {
    const int idx = nrow[j];
    v[j] = H[(size_t)idx * 32 + lane];
  }
  sort32h(v);
  float2 o;
  o.x = (float)v[15][0];
  o.y = (float)v[15][1];
  O[(size_t)node * 32 + lane] = o;
}

extern "C" void kernel_launch(void* const* d_in, const int* in_sizes, int n_in,
                              void* d_out, int out_size, void* d_ws, size_t ws_size,
                              hipStream_t stream) {
  const float* feat = (const float*)d_in[0];   // [50000,512]
  const float* W1   = (const float*)d_in[1];   // [512,128]
  const float* b1   = (const float*)d_in[2];   // [128]
  const float* W2   = (const float*)d_in[3];   // [128,64]
  const float* b2   = (const float*)d_in[4];   // [64]
  const int*   nb   = (const int*)d_in[5];     // [50000,32]
  float* out = (float*)d_out;                  // [50000,64] fp32

  _Float16* h1   = (_Float16*)d_ws;                 // 12.8 MB
  _Float16* med1 = h1 + (size_t)NN * 128;           // 12.8 MB
  _Float16* w1t  = med1 + (size_t)NN * 128;         // 128 KB  [128][512]
  _Float16* w2t  = w1t + 128 * 512;                 // 16 KB   [64][128]
  _Float16* h2b  = h1;                              // reuse (h1 dead)

  prep<<<dim3(288), dim3(256), 0, stream>>>(W1, W2, w1t, w2t);
  gemm1_mfma<<<dim3((NN + 63) / 64), dim3(256), 0, stream>>>(feat, w1t, b1, h1, NN);
  median_relu1<<<dim3(NN / 4), dim3(256), 0, stream>>>(
      (const h2*)h1, nb, (h2*)med1);
  gemm2_mfma<<<dim3((NN + 63) / 64), dim3(256), 0, stream>>>(med1, w2t, b2, h2b, NN);
  median2<<<dim3(NN / 8), dim3(256), 0, stream>>>(
      (const h2*)h2b, nb, (float2*)out);
}

// Round 8
// 257.628 us; speedup vs baseline: 1.1665x; 1.1338x over previous
//
#include <hip/hip_runtime.h>
#include <cstddef>

#define NN   50000
#define KNB  32

typedef _Float16 h2    __attribute__((ext_vector_type(2)));
typedef _Float16 half8 __attribute__((ext_vector_type(8)));
typedef float    f4    __attribute__((ext_vector_type(4)));
typedef float    f8    __attribute__((ext_vector_type(8)));

// ---------------- prep: W1^T and W2^T as fp16 [N][K] ----------------------
__global__ __launch_bounds__(256) void prep(const float* __restrict__ W1,
                                            const float* __restrict__ W2,
                                            _Float16* __restrict__ w1t,
                                            _Float16* __restrict__ w2t) {
  const int id = blockIdx.x * 256 + threadIdx.x;
  if (id < 128 * 512) {                     // w1t[n][k] = W1[k][n]
    const int n = id >> 9, k = id & 511;
    w1t[id] = (_Float16)W1[k * 128 + n];
  } else {
    const int id2 = id - 128 * 512;
    if (id2 < 64 * 128) {                   // w2t[n][k] = W2[k][n]
      const int n = id2 >> 7, k = id2 & 127;
      w2t[id2] = (_Float16)W2[k * 64 + n];
    }
  }
}

// ---------------- GEMM1: H1[M,128] = A[M,512]fp32 @ W1 + b1, fp16 out -----
// R7 post-mortem: register-direct B reads = ~9.6M scattered L2 line-requests
// (2048/wave) -> L2-request-rate bound (~5.6 req/cyc/XCD), pipes idle.
// R8: LDS-staged (m97 pattern). B-tile (32x128 fp16, 8 KB) staged ONCE per
// block per K-step with coalesced 64B-per-row loads, shared by all 4 waves
// via ds_read broadcast. A staged coalesced fp32->fp16. Row stride 80 B
// (pad 8 halves): bank alias <=2-way = free (m136).
//   A-frag: m=lane&15, k=(lane>>4)*8+j   B-frag: n=lane&15, same k
//   C/D: col=lane&15, row=(lane>>4)*4+reg   (verified R5-R7)
__global__ __launch_bounds__(256) void gemm1_mfma(
    const float* __restrict__ A, const _Float16* __restrict__ Bt,
    const float* __restrict__ bias, _Float16* __restrict__ C, int M) {
  constexpr int K = 512, BM = 64, BK = 32;
  __shared__ _Float16 Ah[BM][40];     // 5 KB, 80B stride
  __shared__ _Float16 Bh[128][40];    // 10 KB
  const int tid  = threadIdx.x;
  const int wave = tid >> 6;
  const int lane = tid & 63;
  const int mr   = lane & 15;
  const int kg   = lane >> 4;
  const int m0   = blockIdx.x * BM;

  // staging maps: 4 threads per row, 16B (8 elems) per thread
  const int srow = tid >> 2;          // 0..63
  const int sseg = (tid & 3) * 8;     // elem offset 0,8,16,24
  int aRow = m0 + srow;
  if (aRow >= M) aRow = M - 1;        // clamp; garbage rows dropped at store
  const float*    ap  = A  + (size_t)aRow * K + sseg;
  const _Float16* bp0 = Bt + (size_t)srow * K + sseg;          // rows 0..63
  const _Float16* bp1 = Bt + (size_t)(64 + srow) * K + sseg;   // rows 64..127

  f4 acc[8] = {};

  for (int k0 = 0; k0 < K; k0 += BK) {
    // coalesced loads: 4 consecutive lanes cover one contiguous row-chunk
    const f4 t0 = *(const f4*)ap;
    const f4 t1 = *(const f4*)(ap + 4);
    const half8 blo = *(const half8*)bp0;
    const half8 bhi = *(const half8*)bp1;
    const f8 av = {t0[0], t0[1], t0[2], t0[3], t1[0], t1[1], t1[2], t1[3]};
    *(half8*)&Ah[srow][sseg]      = __builtin_convertvector(av, half8);
    *(half8*)&Bh[srow][sseg]      = blo;
    *(half8*)&Bh[64 + srow][sseg] = bhi;
    __syncthreads();

    const half8 af = *(const half8*)&Ah[wave * 16 + mr][kg * 8];
    #pragma unroll
    for (int nt = 0; nt < 8; ++nt) {
      const half8 bf = *(const half8*)&Bh[nt * 16 + mr][kg * 8];
      acc[nt] = __builtin_amdgcn_mfma_f32_16x16x32_f16(af, bf, acc[nt], 0, 0, 0);
    }
    __syncthreads();
    ap += BK;
    bp0 += BK;
    bp1 += BK;
  }

  #pragma unroll
  for (int nt = 0; nt < 8; ++nt) {
    const int col = nt * 16 + mr;
    const float bv = bias[col];
    #pragma unroll
    for (int r = 0; r < 4; ++r) {
      const int row = m0 + wave * 16 + kg * 4 + r;
      if (row < M)
        C[(size_t)row * 128 + col] = (_Float16)(acc[nt][r] + bv);
    }
  }
}

// ---------------- GEMM2: H2[M,64] = A[M,128]fp16 @ W2 + b2, fp16 out ------
// Same LDS-staged structure. BM=64, BN=64, BK=32, 4 K-steps.
__global__ __launch_bounds__(256) void gemm2_mfma(
    const _Float16* __restrict__ A, const _Float16* __restrict__ Bt,
    const float* __restrict__ bias, _Float16* __restrict__ C, int M) {
  constexpr int K = 128, BM = 64, BK = 32;
  __shared__ _Float16 Ah[BM][40];     // 5 KB
  __shared__ _Float16 Bh[64][40];     // 5 KB
  const int tid  = threadIdx.x;
  const int wave = tid >> 6;
  const int lane = tid & 63;
  const int mr   = lane & 15;
  const int kg   = lane >> 4;
  const int m0   = blockIdx.x * BM;

  const int srow = tid >> 2;          // 0..63
  const int sseg = (tid & 3) * 8;
  int aRow = m0 + srow;
  if (aRow >= M) aRow = M - 1;
  const _Float16* ap = A  + (size_t)aRow * K + sseg;
  const _Float16* bp = Bt + (size_t)srow * K + sseg;

  f4 acc[4] = {};

  #pragma unroll
  for (int k0 = 0; k0 < K; k0 += BK) {
    *(half8*)&Ah[srow][sseg] = *(const half8*)ap;
    *(half8*)&Bh[srow][sseg] = *(const half8*)bp;
    __syncthreads();

    const half8 af = *(const half8*)&Ah[wave * 16 + mr][kg * 8];
    #pragma unroll
    for (int nt = 0; nt < 4; ++nt) {
      const half8 bf = *(const half8*)&Bh[nt * 16 + mr][kg * 8];
      acc[nt] = __builtin_amdgcn_mfma_f32_16x16x32_f16(af, bf, acc[nt], 0, 0, 0);
    }
    __syncthreads();
    ap += BK;
    bp += BK;
  }

  #pragma unroll
  for (int nt = 0; nt < 4; ++nt) {
    const int col = nt * 16 + mr;
    const float bv = bias[col];
    #pragma unroll
    for (int r = 0; r < 4; ++r) {
      const int row = m0 + wave * 16 + kg * 4 + r;
      if (row < M)
        C[(size_t)row * 64 + col] = (_Float16)(acc[nt][r] + bv);
    }
  }
}

// ---------------- median machinery (unchanged) ----------------------------
__device__ __forceinline__ void ceh(h2& a, h2& b) {
  h2 lo = __builtin_elementwise_min(a, b);
  h2 hi = __builtin_elementwise_max(a, b);
  a = lo;
  b = hi;
}

// Batcher odd-even mergesort, 32 h2 elements; only v[15] consumed -> DCE.
__device__ __forceinline__ void sort32h(h2 (&v)[32]) {
  #pragma unroll
  for (int p = 1; p < 32; p <<= 1) {
    #pragma unroll
    for (int k = p; k >= 1; k >>= 1) {
      #pragma unroll
      for (int j = k & (p - 1); j + k < 32; j += 2 * k) {
        #pragma unroll
        for (int i = 0; i < k; ++i) {
          if (i + j + k < 32) {
            if ((i + j) / (2 * p) == (i + j + k) / (2 * p)) {
              ceh(v[i + j], v[i + j + k]);
            }
          }
        }
      }
    }
  }
}

// Median over 32 neighbor rows (layer 1, D=128) + ReLU. One wave per node.
__global__ __launch_bounds__(256) void median_relu1(const h2* __restrict__ H,
                                                    const int* __restrict__ nb,
                                                    h2* __restrict__ O) {
  const int node = blockIdx.x * 4 + (threadIdx.x >> 6);
  const int lane = threadIdx.x & 63;
  const int* nrow = nb + (size_t)node * KNB;
  h2 v[32];
  #pragma unroll
  for (int j = 0; j < KNB; ++j) {
    const int idx = nrow[j];
    v[j] = H[(size_t)idx * 64 + lane];
  }
  sort32h(v);
  const h2 z = (h2)((_Float16)0);
  O[(size_t)node * 64 + lane] = __builtin_elementwise_max(v[15], z);
}

// Median over 32 neighbor rows (layer 2, D=64); fp32 output.
__global__ __launch_bounds__(256) void median2(const h2* __restrict__ H,
                                               const int* __restrict__ nb,
                                               float2* __restrict__ O) {
  const int node = blockIdx.x * 8 + (threadIdx.x >> 5);
  const int lane = threadIdx.x & 31;
  const int* nrow = nb + (size_t)node * KNB;
  h2 v[32];
  #pragma unroll
  for (int j = 0; j < KNB; ++j) {
    const int idx = nrow[j];
    v[j] = H[(size_t)idx * 32 + lane];
  }
  sort32h(v);
  float2 o;
  o.x = (float)v[15][0];
  o.y = (float)v[15][1];
  O[(size_t)node * 32 + lane] = o;
}

extern "C" void kernel_launch(void* const* d_in, const int* in_sizes, int n_in,
                              void* d_out, int out_size, void* d_ws, size_t ws_size,
                              hipStream_t stream) {
  const float* feat = (const float*)d_in[0];   // [50000,512]
  const float* W1   = (const float*)d_in[1];   // [512,128]
  const float* b1   = (const float*)d_in[2];   // [128]
  const float* W2   = (const float*)d_in[3];   // [128,64]
  const float* b2   = (const float*)d_in[4];   // [64]
  const int*   nb   = (const int*)d_in[5];     // [50000,32]
  float* out = (float*)d_out;                  // [50000,64] fp32

  _Float16* h1   = (_Float16*)d_ws;                 // 12.8 MB
  _Float16* med1 = h1 + (size_t)NN * 128;           // 12.8 MB
  _Float16* w1t  = med1 + (size_t)NN * 128;         // 128 KB  [128][512]
  _Float16* w2t  = w1t + 128 * 512;                 // 16 KB   [64][128]
  _Float16* h2b  = h1;                              // reuse (h1 dead)

  prep<<<dim3(288), dim3(256), 0, stream>>>(W1, W2, w1t, w2t);
  gemm1_mfma<<<dim3((NN + 63) / 64), dim3(256), 0, stream>>>(feat, w1t, b1, h1, NN);
  median_relu1<<<dim3(NN / 4), dim3(256), 0, stream>>>(
      (const h2*)h1, nb, (h2*)med1);
  gemm2_mfma<<<dim3((NN + 63) / 64), dim3(256), 0, stream>>>(med1, w2t, b2, h2b, NN);
  median2<<<dim3(NN / 8), dim3(256), 0, stream>>>(
      (const h2*)h2b, nb, (float2*)out);
}